// Round 10
// baseline (241.771 us; speedup 1.0000x reference)
//
#include <hip/hip_runtime.h>
#include <cstdint>
#include <cstddef>

#define BB 2
#define CC 256
#define NN 16
#define LL 4096
#define NCH 256         // chunks per direction
#define CL 16           // chunk length
#define LCH 8           // l-chunk per k1 block
#define LOG2E 1.4426950408889634f

__device__ __forceinline__ float softplus_f(float z) {
    return fmaxf(z, 0.f) + log1pf(expf(-fabsf(z)));
}

__device__ __forceinline__ uint32_t pack_bf2(float d, float u) {
    uint32_t lo = (__float_as_uint(d) + 0x8000u) >> 16;
    uint32_t hh = (__float_as_uint(u) + 0x8000u) & 0xffff0000u;
    return hh | lo;
}

// ---------------- K1: delta/u + Bm/Cm, k-split-by-wave (R8 form) ------------
__global__ __launch_bounds__(256) void k1_delta_gemm(
    const float* __restrict__ feat, const float* __restrict__ Wd,
    const float* __restrict__ bd, const float* __restrict__ WB,
    const float* __restrict__ WC, uint32_t* __restrict__ du,
    float* __restrict__ Bm, float* __restrict__ Cm)
{
    int lc = blockIdx.x & 511;          // 512 l-chunks of 8
    int b  = blockIdx.x >> 9;
    int l0 = lc * LCH;
    const float* fbase = feat + (size_t)b * CC * LL;

    int c4   = threadIdx.x & 63;                                   // c quad
    int kq   = __builtin_amdgcn_readfirstlane(threadIdx.x >> 6);   // wave id
    int hi   = (threadIdx.x >> 5) & 1;
    int slot = threadIdx.x & 31;
    int mat  = slot >> 4;               // 0=Bm 1=Cm
    int n    = slot & 15;
    const float* wBC = mat ? WC : WB;

    float accM[8][4] = {};
    float accB[4] = {};

    int kbase = kq * 64;
    #pragma unroll 4
    for (int kk = 0; kk < 64; ++kk) {
        int k = kbase + kk;
        const float* frow = fbase + (size_t)k * LL + l0;   // wave-uniform
        float4 x0 = *(const float4*)(frow);
        float4 x1 = *(const float4*)(frow + 4);
        float4 wv = *(const float4*)&Wd[(size_t)k * CC + (c4 << 2)];
        float wb  = wBC[k * NN + n];
        float xs[8] = {x0.x, x0.y, x0.z, x0.w, x1.x, x1.y, x1.z, x1.w};
        #pragma unroll
        for (int l = 0; l < 8; ++l) {
            accM[l][0] = fmaf(xs[l], wv.x, accM[l][0]);
            accM[l][1] = fmaf(xs[l], wv.y, accM[l][1]);
            accM[l][2] = fmaf(xs[l], wv.z, accM[l][2]);
            accM[l][3] = fmaf(xs[l], wv.w, accM[l][3]);
        }
        accB[0] = fmaf(hi ? x0.y : x0.x, wb, accB[0]);
        accB[1] = fmaf(hi ? x0.w : x0.z, wb, accB[1]);
        accB[2] = fmaf(hi ? x1.y : x1.x, wb, accB[2]);
        accB[3] = fmaf(hi ? x1.w : x1.z, wb, accB[3]);
    }

    __shared__ float red[4 * 8 * 64 * 4];    // 32 KB
    __shared__ float redBC[4 * 2 * 32 * 4];  // 4 KB
    #pragma unroll
    for (int l = 0; l < 8; ++l)
        *(float4*)&red[((kq * 8 + l) * 64 + c4) * 4] =
            make_float4(accM[l][0], accM[l][1], accM[l][2], accM[l][3]);
    *(float4*)&redBC[((kq * 2 + hi) * 32 + slot) * 4] =
        make_float4(accB[0], accB[1], accB[2], accB[3]);
    __syncthreads();

    {
        int lr = threadIdx.x >> 5, slotr = threadIdx.x & 31;
        int jj = lr >> 1, hh = lr & 1;
        float s = 0.f;
        #pragma unroll
        for (int q = 0; q < 4; ++q)
            s += redBC[((q * 2 + hh) * 32 + slotr) * 4 + jj];
        int mr = slotr >> 4, nr = slotr & 15;
        (mr ? Cm : Bm)[((size_t)b * LL + l0 + lr) * NN + nr] = s;
    }

    float4 bd4 = *(const float4*)&bd[c4 << 2];
    float2 vx[4];
    #pragma unroll
    for (int j = 0; j < 4; ++j)
        vx[j] = *(const float2*)&fbase[(size_t)(c4 * 4 + j) * LL + l0 + kq * 2];
    #pragma unroll
    for (int lo = 0; lo < 2; ++lo) {
        int l = kq * 2 + lo;
        float z0 = 0.f, z1 = 0.f, z2 = 0.f, z3 = 0.f;
        #pragma unroll
        for (int q = 0; q < 4; ++q) {
            float4 p = *(float4*)&red[((q * 8 + l) * 64 + c4) * 4];
            z0 += p.x; z1 += p.y; z2 += p.z; z3 += p.w;
        }
        float d0 = softplus_f(z0 + bd4.x);
        float d1 = softplus_f(z1 + bd4.y);
        float d2 = softplus_f(z2 + bd4.z);
        float d3 = softplus_f(z3 + bd4.w);
        float x0v = lo ? vx[0].y : vx[0].x;
        float x1v = lo ? vx[1].y : vx[1].x;
        float x2v = lo ? vx[2].y : vx[2].x;
        float x3v = lo ? vx[3].y : vx[3].x;
        uint4 o;
        o.x = pack_bf2(d0, d0 * x0v);
        o.y = pack_bf2(d1, d1 * x1v);
        o.z = pack_bf2(d2, d2 * x2v);
        o.w = pack_bf2(d3, d3 * x3v);
        *(uint4*)&du[((size_t)b * LL + l0 + l) * CC + (c4 << 2)] = o;
    }
}

// ---------------- P1: chunk aggregates. Row blocks compute fwd (d0,d2) AND
// bwd (d1) over the same 16 tokens with du register-cached; P shared (exp of
// sum is order-invariant). Col blocks (d3) fwd only. 1024 blocks. ------------
__global__ __launch_bounds__(256) void p1_aggr(
    const uint32_t* __restrict__ du, const float* __restrict__ Bm,
    const float* __restrict__ A_log, float* __restrict__ Prow,
    float* __restrict__ Sf, float* __restrict__ Sb,
    float* __restrict__ Pcol, float* __restrict__ Scol)
{
    int blk = blockIdx.x;
    int c = threadIdx.x;
    bool isRow = blk < 512;
    int b, ch, p0, inner;
    if (isRow) { b = blk >> 8; ch = blk & 255; p0 = ch * CL; inner = 1; }
    else { int t = blk - 512; b = t >> 8; ch = t & 255;
           p0 = 63 - (ch >> 2) + 1024 * (ch & 3); inner = 64; }

    __shared__ float sBm[CL * NN];
    { int j = c >> 4, nn = c & 15;
      sBm[c] = Bm[((size_t)b * LL + (p0 + inner * j)) * NN + nn]; }
    float A2[NN];
    {
        const float4* al = (const float4*)(A_log + c * NN);
        #pragma unroll
        for (int q = 0; q < 4; ++q) {
            float4 v = al[q];
            A2[q*4+0] = -expf(v.x) * LOG2E;
            A2[q*4+1] = -expf(v.y) * LOG2E;
            A2[q*4+2] = -expf(v.z) * LOG2E;
            A2[q*4+3] = -expf(v.w) * LOG2E;
        }
    }
    __syncthreads();
    const uint32_t* dub = du + (size_t)b * LL * CC + c;
    uint32_t w[CL];
    #pragma unroll
    for (int j = 0; j < CL; ++j)
        w[j] = dub[(size_t)(p0 + inner * j) * CC];

    float Svf[NN] = {};
    float sumd = 0.f;
    #pragma unroll
    for (int j = 0; j < CL; ++j) {
        float dx = __uint_as_float(w[j] << 16);
        float uy = __uint_as_float(w[j] & 0xffff0000u);
        sumd += dx;
        float dA[NN];
        #pragma unroll
        for (int nn = 0; nn < NN; ++nn) dA[nn] = __builtin_amdgcn_exp2f(A2[nn] * dx);
        #pragma unroll
        for (int nn = 0; nn < NN; ++nn)
            Svf[nn] = fmaf(dA[nn], Svf[nn], uy * sBm[j * 16 + nn]);
    }
    size_t base = ((size_t)(b * 256 + ch)) * 4096 + (size_t)c * 16;
    if (isRow) {
        float Svb[NN] = {};
        #pragma unroll
        for (int j = CL - 1; j >= 0; --j) {
            float dx = __uint_as_float(w[j] << 16);
            float uy = __uint_as_float(w[j] & 0xffff0000u);
            float dA[NN];
            #pragma unroll
            for (int nn = 0; nn < NN; ++nn) dA[nn] = __builtin_amdgcn_exp2f(A2[nn] * dx);
            #pragma unroll
            for (int nn = 0; nn < NN; ++nn)
                Svb[nn] = fmaf(dA[nn], Svb[nn], uy * sBm[j * 16 + nn]);
        }
        #pragma unroll
        for (int nn = 0; nn < NN; ++nn) {
            Prow[base + nn] = __builtin_amdgcn_exp2f(A2[nn] * sumd);
            Sf[base + nn]   = Svf[nn];
            Sb[base + nn]   = Svb[nn];
        }
    } else {
        #pragma unroll
        for (int nn = 0; nn < NN; ++nn) {
            Pcol[base + nn] = __builtin_amdgcn_exp2f(A2[nn] * sumd);
            Scol[base + nn] = Svf[nn];
        }
    }
}

// ---------------- P2: scan 256 chunk aggregates per direction -> Hin --------
__global__ __launch_bounds__(128) void p2_scan(
    const float* __restrict__ Prow, const float* __restrict__ Sf,
    const float* __restrict__ Sb, const float* __restrict__ Pcol,
    const float* __restrict__ Scol, float* __restrict__ Hin)
{
    int r = blockIdx.x * 128 + threadIdx.x;   // 32768 rows
    int cn = r & 4095;
    int db = r >> 12;
    int d = db >> 1;
    int b = db & 1;
    const float* Pp = (d == 3) ? Pcol : Prow;
    const float* Sp = (d == 3) ? Scol : ((d == 1) ? Sb : Sf);
    const size_t obase = ((size_t)db * 256) * 4096 + cn;
    float h = 0.f;
    for (int g = 0; g < 32; ++g) {
        float pv[8], sv[8];
        #pragma unroll
        for (int i = 0; i < 8; ++i) {
            int ch = g * 8 + i;
            int chm;
            if (d == 1)      chm = 255 - ch;
            else if (d == 2) chm = (63 - (ch >> 2)) * 4 + (ch & 3);
            else             chm = ch;
            size_t ix = ((size_t)(b * 256 + chm)) * 4096 + cn;
            pv[i] = Pp[ix];
            sv[i] = Sp[ix];
        }
        #pragma unroll
        for (int i = 0; i < 8; ++i) {
            Hin[obase + (size_t)(g * 8 + i) * 4096] = h;
            h = fmaf(pv[i], h, sv[i]);
        }
    }
}

// ---------------- P3: replay. Row blocks: fwd (h0,h2) + bwd (h1) over the
// same register-cached du chunk -> single pre-summed yR write. Col: d3 -> yC.
__global__ __launch_bounds__(256) void p3_replay(
    const uint32_t* __restrict__ du, const float* __restrict__ Bm,
    const float* __restrict__ Cm, const float* __restrict__ A_log,
    const float* __restrict__ Hin, float* __restrict__ yR,
    float* __restrict__ yC)
{
    int blk = blockIdx.x;
    int c = threadIdx.x;
    bool isRow = blk < 512;
    int b, ch, p0, inner;
    if (isRow) { b = blk >> 8; ch = blk & 255; p0 = ch * CL; inner = 1; }
    else { int t = blk - 512; b = t >> 8; ch = t & 255;
           p0 = 63 - (ch >> 2) + 1024 * (ch & 3); inner = 64; }

    __shared__ float sBm[CL * NN];
    __shared__ float sCm[CL * NN];
    __shared__ float sY[CL * CC];        // 16 KB (per-thread scratch, no sharing)
    { int j = c >> 4, nn = c & 15;
      size_t o = ((size_t)b * LL + (p0 + inner * j)) * NN + nn;
      sBm[c] = Bm[o];
      sCm[c] = Cm[o]; }
    float A2[NN];
    {
        const float4* al = (const float4*)(A_log + c * NN);
        #pragma unroll
        for (int q = 0; q < 4; ++q) {
            float4 v = al[q];
            A2[q*4+0] = -expf(v.x) * LOG2E;
            A2[q*4+1] = -expf(v.y) * LOG2E;
            A2[q*4+2] = -expf(v.z) * LOG2E;
            A2[q*4+3] = -expf(v.w) * LOG2E;
        }
    }
    __syncthreads();
    const uint32_t* dub = du + (size_t)b * LL * CC + c;
    uint32_t w[CL];
    #pragma unroll
    for (int j = 0; j < CL; ++j)
        w[j] = dub[(size_t)(p0 + inner * j) * CC];

    if (isRow) {
        // h-ins: d0 at ch, d2 at g2(ch), d1 at 255-ch (loaded before bwd)
        int g2 = (63 - (ch >> 2)) * 4 + (ch & 3);
        float h0[NN], h2[NN];
        {
            const float4* hp0 = (const float4*)(Hin + ((size_t)((0 * 2 + b) * 256 + ch) * 4096) + (size_t)c * 16);
            const float4* hp2 = (const float4*)(Hin + ((size_t)((2 * 2 + b) * 256 + g2) * 4096) + (size_t)c * 16);
            #pragma unroll
            for (int q = 0; q < 4; ++q) {
                float4 v0 = hp0[q], v2 = hp2[q];
                h0[q*4+0]=v0.x; h0[q*4+1]=v0.y; h0[q*4+2]=v0.z; h0[q*4+3]=v0.w;
                h2[q*4+0]=v2.x; h2[q*4+1]=v2.y; h2[q*4+2]=v2.z; h2[q*4+3]=v2.w;
            }
        }
        #pragma unroll
        for (int j = 0; j < CL; ++j) {
            float dx = __uint_as_float(w[j] << 16);
            float uy = __uint_as_float(w[j] & 0xffff0000u);
            float dA[NN];
            #pragma unroll
            for (int nn = 0; nn < NN; ++nn) dA[nn] = __builtin_amdgcn_exp2f(A2[nn] * dx);
            float yv = 0.f;
            #pragma unroll
            for (int nn = 0; nn < NN; ++nn) {
                float Bu = uy * sBm[j * 16 + nn];
                float cm = sCm[j * 16 + nn];
                h0[nn] = fmaf(dA[nn], h0[nn], Bu);
                h2[nn] = fmaf(dA[nn], h2[nn], Bu);
                yv = fmaf(h0[nn] + h2[nn], cm, yv);
            }
            sY[j * CC + c] = yv;
        }
        float h1[NN];
        {
            const float4* hp1 = (const float4*)(Hin + ((size_t)((1 * 2 + b) * 256 + (255 - ch)) * 4096) + (size_t)c * 16);
            #pragma unroll
            for (int q = 0; q < 4; ++q) {
                float4 v = hp1[q];
                h1[q*4+0]=v.x; h1[q*4+1]=v.y; h1[q*4+2]=v.z; h1[q*4+3]=v.w;
            }
        }
        #pragma unroll
        for (int j = CL - 1; j >= 0; --j) {
            float dx = __uint_as_float(w[j] << 16);
            float uy = __uint_as_float(w[j] & 0xffff0000u);
            float dA[NN];
            #pragma unroll
            for (int nn = 0; nn < NN; ++nn) dA[nn] = __builtin_amdgcn_exp2f(A2[nn] * dx);
            float y1 = 0.f;
            #pragma unroll
            for (int nn = 0; nn < NN; ++nn) {
                float Bu = uy * sBm[j * 16 + nn];
                h1[nn] = fmaf(dA[nn], h1[nn], Bu);
                y1 = fmaf(h1[nn], sCm[j * 16 + nn], y1);
            }
            yR[((size_t)b * LL + p0 + j) * CC + c] = 0.25f * (sY[j * CC + c] + y1);
        }
    } else {
        float h[NN];
        {
            const float4* hp = (const float4*)(Hin + ((size_t)((3 * 2 + b) * 256 + ch) * 4096) + (size_t)c * 16);
            #pragma unroll
            for (int q = 0; q < 4; ++q) {
                float4 v = hp[q];
                h[q*4+0]=v.x; h[q*4+1]=v.y; h[q*4+2]=v.z; h[q*4+3]=v.w;
            }
        }
        #pragma unroll
        for (int j = 0; j < CL; ++j) {
            float dx = __uint_as_float(w[j] << 16);
            float uy = __uint_as_float(w[j] & 0xffff0000u);
            float dA[NN];
            #pragma unroll
            for (int nn = 0; nn < NN; ++nn) dA[nn] = __builtin_amdgcn_exp2f(A2[nn] * dx);
            float yv = 0.f;
            #pragma unroll
            for (int nn = 0; nn < NN; ++nn) {
                float Bu = uy * sBm[j * 16 + nn];
                h[nn] = fmaf(dA[nn], h[nn], Bu);
                yv = fmaf(h[nn], sCm[j * 16 + nn], yv);
            }
            yC[((size_t)b * LL + p0 + inner * j) * CC + c] = 0.25f * yv;
        }
    }
}

// ---------------- K6: sum 2 y-buffers + x*D, transpose to (B,C,L) -----------
__global__ __launch_bounds__(256) void k6_reduce(
    const float* __restrict__ feat, const float* __restrict__ D,
    const float* __restrict__ yR, const float* __restrict__ yC,
    float* __restrict__ out)
{
    int pt = blockIdx.x & 63;
    int ct = (blockIdx.x >> 6) & 3;
    int b  = blockIdx.x >> 8;
    int p0 = pt * 64, c0 = ct * 64;
    __shared__ float tile[64 * 65];
    {
        int cl = threadIdx.x & 63;
        int pg = threadIdx.x >> 6;
        #pragma unroll
        for (int pp = 0; pp < 16; ++pp) {
            int pl = pp * 4 + pg;
            size_t ix = ((size_t)b * LL + p0 + pl) * CC + c0 + cl;
            tile[cl * 65 + pl] = yR[ix] + yC[ix];
        }
    }
    __syncthreads();
    {
        int pl = threadIdx.x & 63;
        int cg = threadIdx.x >> 6;
        #pragma unroll
        for (int cc = 0; cc < 16; ++cc) {
            int cloc = cc * 4 + cg;
            int c = c0 + cloc;
            size_t o = ((size_t)b * CC + c) * LL + p0 + pl;
            out[o] = tile[cloc * 65 + pl] + feat[o] * D[c];
        }
    }
}

extern "C" void kernel_launch(void* const* d_in, const int* in_sizes, int n_in,
                              void* d_out, int out_size, void* d_ws, size_t ws_size,
                              hipStream_t stream)
{
    const float* feat  = (const float*)d_in[0];
    const float* A_log = (const float*)d_in[1];
    const float* D     = (const float*)d_in[2];
    const float* Wd    = (const float*)d_in[3];
    const float* bd    = (const float*)d_in[4];
    const float* WB    = (const float*)d_in[5];
    const float* WC    = (const float*)d_in[6];
    float* out = (float*)d_out;

    float* ws  = (float*)d_ws;
    uint32_t* du = (uint32_t*)ws;                         //  2,097,152 u32 (bf16x2)
    float* Bm   = ws   + (size_t)2097152;                 //    131,072
    float* Cm   = Bm   + (size_t)131072;                  //    131,072
    float* Prow = Cm   + (size_t)131072;                  //  2,097,152
    float* Sf   = Prow + (size_t)2097152;                 //  2,097,152
    float* Sb   = Sf   + (size_t)2097152;                 //  2,097,152
    float* Pcol = Sb   + (size_t)2097152;                 //  2,097,152
    float* Scol = Pcol + (size_t)2097152;                 //  2,097,152
    float* Hin  = Scol + (size_t)2097152;                 //  8,388,608
    float* yR   = Hin  + (size_t)8388608;                 //  2,097,152
    float* yC   = yR   + (size_t)2097152;                 //  2,097,152
    // total ~25.4M floats ~102 MB

    k1_delta_gemm<<<1024, 256, 0, stream>>>(feat, Wd, bd, WB, WC, du, Bm, Cm);
    p1_aggr<<<1024, 256, 0, stream>>>(du, Bm, A_log, Prow, Sf, Sb, Pcol, Scol);
    p2_scan<<<256, 128, 0, stream>>>(Prow, Sf, Sb, Pcol, Scol, Hin);
    p3_replay<<<1024, 256, 0, stream>>>(du, Bm, Cm, A_log, Hin, yR, yC);
    k6_reduce<<<512, 256, 0, stream>>>(feat, D, yR, yC, out);
}

// Round 11
// 159.926 us; speedup vs baseline: 1.5118x; 1.5118x over previous
//
#include <hip/hip_runtime.h>
#include <cstdint>
#include <cstddef>

#define BB 2
#define CC 256
#define NN 16
#define LL 4096
#define NCH 128
#define CLEN 32
#define LCH 8           // l-chunk per k1 block
#define LOG2E 1.4426950408889634f

__device__ __forceinline__ float softplus_f(float z) {
    return fmaxf(z, 0.f) + log1pf(expf(-fabsf(z)));
}

__device__ __forceinline__ uint32_t pack_bf2(float d, float u) {
    uint32_t lo = (__float_as_uint(d) + 0x8000u) >> 16;
    uint32_t hh = (__float_as_uint(u) + 0x8000u) & 0xffff0000u;
    return hh | lo;
}

// ---------------- K1: delta/u + Bm/Cm, k-split-by-wave (R8 form) ------------
__global__ __launch_bounds__(256) void k1_delta_gemm(
    const float* __restrict__ feat, const float* __restrict__ Wd,
    const float* __restrict__ bd, const float* __restrict__ WB,
    const float* __restrict__ WC, uint32_t* __restrict__ du,
    float* __restrict__ Bm, float* __restrict__ Cm)
{
    int lc = blockIdx.x & 511;          // 512 l-chunks of 8
    int b  = blockIdx.x >> 9;
    int l0 = lc * LCH;
    const float* fbase = feat + (size_t)b * CC * LL;

    int c4   = threadIdx.x & 63;                                   // c quad
    int kq   = __builtin_amdgcn_readfirstlane(threadIdx.x >> 6);   // wave id
    int hi   = (threadIdx.x >> 5) & 1;
    int slot = threadIdx.x & 31;
    int mat  = slot >> 4;               // 0=Bm 1=Cm
    int n    = slot & 15;
    const float* wBC = mat ? WC : WB;

    float accM[8][4] = {};
    float accB[4] = {};

    int kbase = kq * 64;
    #pragma unroll 4
    for (int kk = 0; kk < 64; ++kk) {
        int k = kbase + kk;
        const float* frow = fbase + (size_t)k * LL + l0;   // wave-uniform
        float4 x0 = *(const float4*)(frow);
        float4 x1 = *(const float4*)(frow + 4);
        float4 wv = *(const float4*)&Wd[(size_t)k * CC + (c4 << 2)];
        float wb  = wBC[k * NN + n];
        float xs[8] = {x0.x, x0.y, x0.z, x0.w, x1.x, x1.y, x1.z, x1.w};
        #pragma unroll
        for (int l = 0; l < 8; ++l) {
            accM[l][0] = fmaf(xs[l], wv.x, accM[l][0]);
            accM[l][1] = fmaf(xs[l], wv.y, accM[l][1]);
            accM[l][2] = fmaf(xs[l], wv.z, accM[l][2]);
            accM[l][3] = fmaf(xs[l], wv.w, accM[l][3]);
        }
        accB[0] = fmaf(hi ? x0.y : x0.x, wb, accB[0]);
        accB[1] = fmaf(hi ? x0.w : x0.z, wb, accB[1]);
        accB[2] = fmaf(hi ? x1.y : x1.x, wb, accB[2]);
        accB[3] = fmaf(hi ? x1.w : x1.z, wb, accB[3]);
    }

    __shared__ float red[4 * 8 * 64 * 4];    // 32 KB
    __shared__ float redBC[4 * 2 * 32 * 4];  // 4 KB
    #pragma unroll
    for (int l = 0; l < 8; ++l)
        *(float4*)&red[((kq * 8 + l) * 64 + c4) * 4] =
            make_float4(accM[l][0], accM[l][1], accM[l][2], accM[l][3]);
    *(float4*)&redBC[((kq * 2 + hi) * 32 + slot) * 4] =
        make_float4(accB[0], accB[1], accB[2], accB[3]);
    __syncthreads();

    {
        int lr = threadIdx.x >> 5, slotr = threadIdx.x & 31;
        int jj = lr >> 1, hh = lr & 1;
        float s = 0.f;
        #pragma unroll
        for (int q = 0; q < 4; ++q)
            s += redBC[((q * 2 + hh) * 32 + slotr) * 4 + jj];
        int mr = slotr >> 4, nr = slotr & 15;
        (mr ? Cm : Bm)[((size_t)b * LL + l0 + lr) * NN + nr] = s;
    }

    float4 bd4 = *(const float4*)&bd[c4 << 2];
    float2 vx[4];
    #pragma unroll
    for (int j = 0; j < 4; ++j)
        vx[j] = *(const float2*)&fbase[(size_t)(c4 * 4 + j) * LL + l0 + kq * 2];
    #pragma unroll
    for (int lo = 0; lo < 2; ++lo) {
        int l = kq * 2 + lo;
        float z0 = 0.f, z1 = 0.f, z2 = 0.f, z3 = 0.f;
        #pragma unroll
        for (int q = 0; q < 4; ++q) {
            float4 p = *(float4*)&red[((q * 8 + l) * 64 + c4) * 4];
            z0 += p.x; z1 += p.y; z2 += p.z; z3 += p.w;
        }
        float d0 = softplus_f(z0 + bd4.x);
        float d1 = softplus_f(z1 + bd4.y);
        float d2 = softplus_f(z2 + bd4.z);
        float d3 = softplus_f(z3 + bd4.w);
        float x0v = lo ? vx[0].y : vx[0].x;
        float x1v = lo ? vx[1].y : vx[1].x;
        float x2v = lo ? vx[2].y : vx[2].x;
        float x3v = lo ? vx[3].y : vx[3].x;
        uint4 o;
        o.x = pack_bf2(d0, d0 * x0v);
        o.y = pack_bf2(d1, d1 * x1v);
        o.z = pack_bf2(d2, d2 * x2v);
        o.w = pack_bf2(d3, d3 * x3v);
        *(uint4*)&du[((size_t)b * LL + l0 + l) * CC + (c4 << 2)] = o;
    }
}

// ---------------- P1: per-chunk aggregates, full 32-deep upfront prefetch ---
__global__ __launch_bounds__(256) void p1_aggr(
    const uint32_t* __restrict__ du, const float* __restrict__ Bm,
    const float* __restrict__ A_log, float* __restrict__ P, float* __restrict__ S)
{
    int blk = blockIdx.x;
    int cls = blk >> 8;
    int b   = (blk >> 7) & 1;
    int ch  = blk & 127;
    int p0, inner;
    if (cls == 0)      { p0 = 32 * ch;        inner = 1; }
    else if (cls == 1) { p0 = 4095 - 32 * ch; inner = -1; }
    else               { p0 = 63 - (ch >> 1) + 2048 * (ch & 1); inner = 64; }
    int c = threadIdx.x;
    __shared__ float sBm[CLEN * NN];
    for (int i = threadIdx.x; i < CLEN * NN; i += 256) {
        int j = i >> 4, nn = i & 15;
        sBm[i] = Bm[((size_t)b * LL + (p0 + inner * j)) * NN + nn];
    }
    // all 32 du loads in flight before the loop (one vmcnt drain)
    const uint32_t* dub = du + (size_t)b * LL * CC + c;
    uint32_t w[CLEN];
    #pragma unroll
    for (int j = 0; j < CLEN; ++j)
        w[j] = dub[(size_t)(p0 + inner * j) * CC];
    float A2[NN];
    {
        const float4* al = (const float4*)(A_log + c * NN);
        #pragma unroll
        for (int q = 0; q < 4; ++q) {
            float4 v = al[q];
            A2[q*4+0] = -expf(v.x) * LOG2E;
            A2[q*4+1] = -expf(v.y) * LOG2E;
            A2[q*4+2] = -expf(v.z) * LOG2E;
            A2[q*4+3] = -expf(v.w) * LOG2E;
        }
    }
    __syncthreads();
    float Sv[NN] = {};
    float sumd = 0.f;
    #pragma unroll
    for (int j = 0; j < CLEN; ++j) {
        float dx = __uint_as_float(w[j] << 16);
        float uy = __uint_as_float(w[j] & 0xffff0000u);
        sumd += dx;
        float dA[NN];
        #pragma unroll
        for (int nn = 0; nn < NN; ++nn) dA[nn] = __builtin_amdgcn_exp2f(A2[nn] * dx);
        #pragma unroll
        for (int nn = 0; nn < NN; ++nn)
            Sv[nn] = fmaf(dA[nn], Sv[nn], uy * sBm[j * 16 + nn]);
    }
    size_t base = ((size_t)((cls * 2 + b) * 128 + ch)) * 4096 + (size_t)c * 16;
    #pragma unroll
    for (int nn = 0; nn < NN; ++nn) {
        P[base + nn] = __builtin_amdgcn_exp2f(A2[nn] * sumd);
        S[base + nn] = Sv[nn];
    }
}

// ---------------- P2: scan chunk aggregates per direction -> Hin ------------
__global__ __launch_bounds__(128) void p2_scan(
    const float* __restrict__ P, const float* __restrict__ S, float* __restrict__ Hin)
{
    int r = blockIdx.x * 128 + threadIdx.x;   // 32768 rows
    int cn = r & 4095;
    int db = r >> 12;
    int d = db >> 1;
    int cls = (d == 1) ? 1 : ((d == 3) ? 2 : 0);
    int b = db & 1;
    const size_t cbase = ((size_t)(cls * 2 + b) * 128) * 4096 + cn;
    const size_t obase = ((size_t)db * 128) * 4096 + cn;
    float h = 0.f;
    for (int g = 0; g < 16; ++g) {
        float pv[8], sv[8];
        #pragma unroll
        for (int i = 0; i < 8; ++i) {
            int ch = g * 8 + i;
            int chm = (d == 2) ? (126 - 2 * (ch >> 1) + (ch & 1)) : ch;
            size_t ix = cbase + (size_t)chm * 4096;
            pv[i] = P[ix];
            sv[i] = S[ix];
        }
        #pragma unroll
        for (int i = 0; i < 8; ++i) {
            Hin[obase + (size_t)(g * 8 + i) * 4096] = h;
            h = fmaf(pv[i], h, sv[i]);
        }
    }
}

// ---------------- P3: replay, full 32-deep upfront prefetch -----------------
__global__ __launch_bounds__(256) void p3_replay(
    const uint32_t* __restrict__ du, const float* __restrict__ Bm,
    const float* __restrict__ Cm, const float* __restrict__ A_log,
    const float* __restrict__ Hin, float* __restrict__ yA,
    float* __restrict__ yB, float* __restrict__ yC)
{
    int blk = blockIdx.x;
    int sec = blk >> 8;
    int b   = (blk >> 7) & 1;
    int ch  = blk & 127;
    int p0, inner;
    if (sec == 0)      { p0 = 32 * ch;        inner = 1; }
    else if (sec == 1) { p0 = 4095 - 32 * ch; inner = -1; }
    else               { p0 = 63 - (ch >> 1) + 2048 * (ch & 1); inner = 64; }
    int c = threadIdx.x;
    __shared__ float sBm[CLEN * NN];
    __shared__ float sCm[CLEN * NN];
    for (int i = threadIdx.x; i < CLEN * NN; i += 256) {
        int j = i >> 4, nn = i & 15;
        size_t o = ((size_t)b * LL + (p0 + inner * j)) * NN + nn;
        sBm[i] = Bm[o];
        sCm[i] = Cm[o];
    }
    const uint32_t* dub = du + (size_t)b * LL * CC + c;
    uint32_t w[CLEN];
    #pragma unroll
    for (int j = 0; j < CLEN; ++j)
        w[j] = dub[(size_t)(p0 + inner * j) * CC];
    float A2[NN];
    {
        const float4* al = (const float4*)(A_log + c * NN);
        #pragma unroll
        for (int q = 0; q < 4; ++q) {
            float4 v = al[q];
            A2[q*4+0] = -expf(v.x) * LOG2E;
            A2[q*4+1] = -expf(v.y) * LOG2E;
            A2[q*4+2] = -expf(v.z) * LOG2E;
            A2[q*4+3] = -expf(v.w) * LOG2E;
        }
    }

    if (sec == 0) {
        int ch2 = 126 - (ch & ~1) + (ch & 1);
        float h0[NN], h2[NN];
        {
            const float4* hp0 = (const float4*)(Hin + ((size_t)(0 * 2 + b) * 128 + ch)  * 4096 + (size_t)c * 16);
            const float4* hp2 = (const float4*)(Hin + ((size_t)(2 * 2 + b) * 128 + ch2) * 4096 + (size_t)c * 16);
            #pragma unroll
            for (int q = 0; q < 4; ++q) {
                float4 v0 = hp0[q], v2 = hp2[q];
                h0[q*4+0]=v0.x; h0[q*4+1]=v0.y; h0[q*4+2]=v0.z; h0[q*4+3]=v0.w;
                h2[q*4+0]=v2.x; h2[q*4+1]=v2.y; h2[q*4+2]=v2.z; h2[q*4+3]=v2.w;
            }
        }
        __syncthreads();
        #pragma unroll
        for (int j = 0; j < CLEN; ++j) {
            float dx = __uint_as_float(w[j] << 16);
            float uy = __uint_as_float(w[j] & 0xffff0000u);
            float dA[NN];
            #pragma unroll
            for (int nn = 0; nn < NN; ++nn) dA[nn] = __builtin_amdgcn_exp2f(A2[nn] * dx);
            float y0v = 0.f, y2v = 0.f;
            #pragma unroll
            for (int nn = 0; nn < NN; ++nn) {
                float Bu = uy * sBm[j * 16 + nn];
                float cm = sCm[j * 16 + nn];
                h0[nn] = fmaf(dA[nn], h0[nn], Bu);
                h2[nn] = fmaf(dA[nn], h2[nn], Bu);
                y0v = fmaf(h0[nn], cm, y0v);
                y2v = fmaf(h2[nn], cm, y2v);
            }
            yA[((size_t)b * LL + p0 + j) * CC + c] = 0.25f * (y0v + y2v);
        }
    } else {
        int d = (sec == 1) ? 1 : 3;
        float h[NN];
        {
            const float4* hp = (const float4*)(Hin + ((size_t)(d * 2 + b) * 128 + ch) * 4096 + (size_t)c * 16);
            #pragma unroll
            for (int q = 0; q < 4; ++q) {
                float4 v = hp[q];
                h[q*4+0]=v.x; h[q*4+1]=v.y; h[q*4+2]=v.z; h[q*4+3]=v.w;
            }
        }
        __syncthreads();
        float* yD = (sec == 1) ? yB : yC;
        #pragma unroll
        for (int j = 0; j < CLEN; ++j) {
            float dx = __uint_as_float(w[j] << 16);
            float uy = __uint_as_float(w[j] & 0xffff0000u);
            float dA[NN];
            #pragma unroll
            for (int nn = 0; nn < NN; ++nn) dA[nn] = __builtin_amdgcn_exp2f(A2[nn] * dx);
            float yv = 0.f;
            #pragma unroll
            for (int nn = 0; nn < NN; ++nn) {
                float Bu = uy * sBm[j * 16 + nn];
                h[nn] = fmaf(dA[nn], h[nn], Bu);
                yv = fmaf(h[nn], sCm[j * 16 + nn], yv);
            }
            yD[((size_t)b * LL + p0 + inner * j) * CC + c] = 0.25f * yv;
        }
    }
}

// ---------------- K6: sum 3 y-buffers + x*D, transpose to (B,C,L) -----------
__global__ __launch_bounds__(256) void k6_reduce(
    const float* __restrict__ feat, const float* __restrict__ D,
    const float* __restrict__ yA, const float* __restrict__ yB,
    const float* __restrict__ yC, float* __restrict__ out)
{
    int pt = blockIdx.x & 63;
    int ct = (blockIdx.x >> 6) & 3;
    int b  = blockIdx.x >> 8;
    int p0 = pt * 64, c0 = ct * 64;
    __shared__ float tile[64 * 65];
    {
        int cl = threadIdx.x & 63;
        int pg = threadIdx.x >> 6;
        #pragma unroll
        for (int pp = 0; pp < 16; ++pp) {
            int pl = pp * 4 + pg;
            size_t ix = ((size_t)b * LL + p0 + pl) * CC + c0 + cl;
            tile[cl * 65 + pl] = yA[ix] + yB[ix] + yC[ix];
        }
    }
    __syncthreads();
    {
        int pl = threadIdx.x & 63;
        int cg = threadIdx.x >> 6;
        #pragma unroll
        for (int cc = 0; cc < 16; ++cc) {
            int cloc = cc * 4 + cg;
            int c = c0 + cloc;
            size_t o = ((size_t)b * CC + c) * LL + p0 + pl;
            out[o] = tile[cloc * 65 + pl] + feat[o] * D[c];
        }
    }
}

extern "C" void kernel_launch(void* const* d_in, const int* in_sizes, int n_in,
                              void* d_out, int out_size, void* d_ws, size_t ws_size,
                              hipStream_t stream)
{
    const float* feat  = (const float*)d_in[0];
    const float* A_log = (const float*)d_in[1];
    const float* D     = (const float*)d_in[2];
    const float* Wd    = (const float*)d_in[3];
    const float* bd    = (const float*)d_in[4];
    const float* WB    = (const float*)d_in[5];
    const float* WC    = (const float*)d_in[6];
    float* out = (float*)d_out;

    float* ws  = (float*)d_ws;
    uint32_t* du = (uint32_t*)ws;                         //  2,097,152 u32 (bf16x2)
    float* Bm  = ws  + (size_t)2097152;                   //    131,072
    float* Cm  = Bm  + (size_t)131072;                    //    131,072
    float* P   = Cm  + (size_t)131072;                    //  3,145,728 (3 cls)
    float* S   = P   + (size_t)3145728;                   //  3,145,728
    float* Hin = S   + (size_t)3145728;                   //  4,194,304 (4 dirs)
    float* yA  = Hin + (size_t)4194304;                   //  2,097,152
    float* yB  = yA  + (size_t)2097152;                   //  2,097,152
    float* yC  = yB  + (size_t)2097152;                   //  2,097,152

    k1_delta_gemm<<<1024, 256, 0, stream>>>(feat, Wd, bd, WB, WC, du, Bm, Cm);
    p1_aggr<<<768, 256, 0, stream>>>(du, Bm, A_log, P, S);
    p2_scan<<<256, 128, 0, stream>>>(P, S, Hin);
    p3_replay<<<768, 256, 0, stream>>>(du, Bm, Cm, A_log, Hin, yA, yB, yC);
    k6_reduce<<<512, 256, 0, stream>>>(feat, D, yA, yB, yC, out);
}

// Round 14
// 149.983 us; speedup vs baseline: 1.6120x; 1.0663x over previous
//
#include <hip/hip_runtime.h>
#include <cstdint>
#include <cstddef>

#define BB 2
#define CC 256
#define NN 16
#define LL 4096
#define NCH 128
#define CLEN 32
#define LOG2E 1.4426950408889634f

typedef __attribute__((ext_vector_type(8))) short short8;
typedef __attribute__((ext_vector_type(4))) float f32x4;

__device__ __forceinline__ float softplus_f(float z) {
    return fmaxf(z, 0.f) + log1pf(expf(-fabsf(z)));
}

__device__ __forceinline__ uint32_t pack_bf2(float d, float u) {
    uint32_t lo = (__float_as_uint(d) + 0x8000u) >> 16;
    uint32_t hh = (__float_as_uint(u) + 0x8000u) & 0xffff0000u;
    return hh | lo;
}

__device__ __forceinline__ short bf16r(float f) {
    return (short)((__float_as_uint(f) + 0x8000u) >> 16);
}

// ---------------- K1 (MFMA): Z = X@Wd via bf16 matrix cores -----------------
// grid = 1024 = b(2) x lt(128 l-tiles of 32) x ct(4 c-tiles of 64).  [R13 bug:
// launched 2048 with lt&255 -> l0 up to 8160, OOB fault. Fixed decode.]
// block = 32l x 64c tile, 256 thr (4 waves: wq -> m0=(wq&1)*16, n0=(wq>>1)*32).
// Fragments loaded DIRECTLY from global fp32 + cvt (no LDS, no barrier):
//   A[m=lane&15][k=quad*8+j] = feat[k][l0+m0+m]  (16 consecutive l per quad)
//   B[k][n=lane&15]          = Wd[k][c0+n0+nt*16+n] (L1/L2-resident)
//   C/D: col=lane&15, row=quad*4+reg  [m89-verified]
// ct==0 blocks also compute Bm/Cm with a 3rd MFMA reusing the A-frag.
__global__ __launch_bounds__(256) void k1_mfma(
    const float* __restrict__ feat, const float* __restrict__ Wd,
    const float* __restrict__ bd, const float* __restrict__ WB,
    const float* __restrict__ WC, uint32_t* __restrict__ du,
    float* __restrict__ Bm, float* __restrict__ Cm)
{
    int blk = blockIdx.x;               // b*512 + lt*4 + ct
    int b  = blk >> 9;
    int lt = (blk >> 2) & 127;
    int ct = blk & 3;
    int l0 = lt * 32, c0 = ct * 64;
    const float* fbase = feat + (size_t)b * CC * LL;
    int lane = threadIdx.x & 63;
    int wq   = threadIdx.x >> 6;
    int m    = lane & 15;
    int quad = lane >> 4;
    int m0   = (wq & 1) * 16;
    int n0   = (wq >> 1) * 32;
    bool doBC = (ct == 0);
    const float* wBC = (wq >> 1) ? WC : WB;

    f32x4 acc0 = {0.f, 0.f, 0.f, 0.f};
    f32x4 acc1 = {0.f, 0.f, 0.f, 0.f};
    f32x4 accB = {0.f, 0.f, 0.f, 0.f};

    const float* aptr  = fbase + (size_t)(quad * 8) * LL + (l0 + m0 + m);
    const float* b0ptr = Wd    + (size_t)(quad * 8) * CC + (c0 + n0 + m);
    const float* b1ptr = b0ptr + 16;
    const float* bbptr = wBC   + (size_t)(quad * 8) * NN + m;

    for (int ks = 0; ks < 8; ++ks) {
        short8 af, bf0, bf1;
        #pragma unroll
        for (int j = 0; j < 8; ++j) {
            size_t kr = (size_t)(ks * 32 + j);
            af[j]  = bf16r(aptr [kr * LL]);
            bf0[j] = bf16r(b0ptr[kr * CC]);
            bf1[j] = bf16r(b1ptr[kr * CC]);
        }
        acc0 = __builtin_amdgcn_mfma_f32_16x16x32_bf16(af, bf0, acc0, 0, 0, 0);
        acc1 = __builtin_amdgcn_mfma_f32_16x16x32_bf16(af, bf1, acc1, 0, 0, 0);
        if (doBC) {
            short8 bbf;
            #pragma unroll
            for (int j = 0; j < 8; ++j)
                bbf[j] = bf16r(bbptr[(size_t)(ks * 32 + j) * NN]);
            accB = __builtin_amdgcn_mfma_f32_16x16x32_bf16(af, bbf, accB, 0, 0, 0);
        }
    }

    if (doBC) {
        float* dst = (wq >> 1) ? Cm : Bm;
        #pragma unroll
        for (int r = 0; r < 4; ++r) {
            int l = l0 + m0 + quad * 4 + r;
            dst[((size_t)b * LL + l) * NN + m] = accB[r];
        }
    }

    float bd0 = bd[c0 + n0 + m];
    float bd1 = bd[c0 + n0 + 16 + m];
    int cA = c0 + n0 + m;
    int cB = cA + 16;
    #pragma unroll
    for (int r = 0; r < 4; ++r) {
        int l = l0 + m0 + quad * 4 + r;
        float d0 = softplus_f(acc0[r] + bd0);
        float d1 = softplus_f(acc1[r] + bd1);
        float x0 = fbase[(size_t)cA * LL + l];
        float x1 = fbase[(size_t)cB * LL + l];
        du[((size_t)b * LL + l) * CC + cA] = pack_bf2(d0, d0 * x0);
        du[((size_t)b * LL + l) * CC + cB] = pack_bf2(d1, d1 * x1);
    }
}

// ---------------- P1: per-chunk aggregates, full 32-deep upfront prefetch ---
__global__ __launch_bounds__(256) void p1_aggr(
    const uint32_t* __restrict__ du, const float* __restrict__ Bm,
    const float* __restrict__ A_log, float* __restrict__ P, float* __restrict__ S)
{
    int blk = blockIdx.x;
    int cls = blk >> 8;
    int b   = (blk >> 7) & 1;
    int ch  = blk & 127;
    int p0, inner;
    if (cls == 0)      { p0 = 32 * ch;        inner = 1; }
    else if (cls == 1) { p0 = 4095 - 32 * ch; inner = -1; }
    else               { p0 = 63 - (ch >> 1) + 2048 * (ch & 1); inner = 64; }
    int c = threadIdx.x;
    __shared__ float sBm[CLEN * NN];
    for (int i = threadIdx.x; i < CLEN * NN; i += 256) {
        int j = i >> 4, nn = i & 15;
        sBm[i] = Bm[((size_t)b * LL + (p0 + inner * j)) * NN + nn];
    }
    const uint32_t* dub = du + (size_t)b * LL * CC + c;
    uint32_t w[CLEN];
    #pragma unroll
    for (int j = 0; j < CLEN; ++j)
        w[j] = dub[(size_t)(p0 + inner * j) * CC];
    float A2[NN];
    {
        const float4* al = (const float4*)(A_log + c * NN);
        #pragma unroll
        for (int q = 0; q < 4; ++q) {
            float4 v = al[q];
            A2[q*4+0] = -expf(v.x) * LOG2E;
            A2[q*4+1] = -expf(v.y) * LOG2E;
            A2[q*4+2] = -expf(v.z) * LOG2E;
            A2[q*4+3] = -expf(v.w) * LOG2E;
        }
    }
    __syncthreads();
    float Sv[NN] = {};
    float sumd = 0.f;
    #pragma unroll
    for (int j = 0; j < CLEN; ++j) {
        float dx = __uint_as_float(w[j] << 16);
        float uy = __uint_as_float(w[j] & 0xffff0000u);
        sumd += dx;
        float dA[NN];
        #pragma unroll
        for (int nn = 0; nn < NN; ++nn) dA[nn] = __builtin_amdgcn_exp2f(A2[nn] * dx);
        #pragma unroll
        for (int nn = 0; nn < NN; ++nn)
            Sv[nn] = fmaf(dA[nn], Sv[nn], uy * sBm[j * 16 + nn]);
    }
    size_t base = ((size_t)((cls * 2 + b) * 128 + ch)) * 4096 + (size_t)c * 16;
    #pragma unroll
    for (int nn = 0; nn < NN; ++nn) {
        P[base + nn] = __builtin_amdgcn_exp2f(A2[nn] * sumd);
        S[base + nn] = Sv[nn];
    }
}

// ---------------- P2: scan chunk aggregates per direction -> Hin ------------
__global__ __launch_bounds__(128) void p2_scan(
    const float* __restrict__ P, const float* __restrict__ S, float* __restrict__ Hin)
{
    int r = blockIdx.x * 128 + threadIdx.x;   // 32768 rows
    int cn = r & 4095;
    int db = r >> 12;
    int d = db >> 1;
    int cls = (d == 1) ? 1 : ((d == 3) ? 2 : 0);
    int b = db & 1;
    const size_t cbase = ((size_t)(cls * 2 + b) * 128) * 4096 + cn;
    const size_t obase = ((size_t)db * 128) * 4096 + cn;
    float h = 0.f;
    for (int g = 0; g < 16; ++g) {
        float pv[8], sv[8];
        #pragma unroll
        for (int i = 0; i < 8; ++i) {
            int ch = g * 8 + i;
            int chm = (d == 2) ? (126 - 2 * (ch >> 1) + (ch & 1)) : ch;
            size_t ix = cbase + (size_t)chm * 4096;
            pv[i] = P[ix];
            sv[i] = S[ix];
        }
        #pragma unroll
        for (int i = 0; i < 8; ++i) {
            Hin[obase + (size_t)(g * 8 + i) * 4096] = h;
            h = fmaf(pv[i], h, sv[i]);
        }
    }
}

// ---------------- P3: replay, full 32-deep upfront prefetch -----------------
__global__ __launch_bounds__(256) void p3_replay(
    const uint32_t* __restrict__ du, const float* __restrict__ Bm,
    const float* __restrict__ Cm, const float* __restrict__ A_log,
    const float* __restrict__ Hin, float* __restrict__ yA,
    float* __restrict__ yB, float* __restrict__ yC)
{
    int blk = blockIdx.x;
    int sec = blk >> 8;
    int b   = (blk >> 7) & 1;
    int ch  = blk & 127;
    int p0, inner;
    if (sec == 0)      { p0 = 32 * ch;        inner = 1; }
    else if (sec == 1) { p0 = 4095 - 32 * ch; inner = -1; }
    else               { p0 = 63 - (ch >> 1) + 2048 * (ch & 1); inner = 64; }
    int c = threadIdx.x;
    __shared__ float sBm[CLEN * NN];
    __shared__ float sCm[CLEN * NN];
    for (int i = threadIdx.x; i < CLEN * NN; i += 256) {
        int j = i >> 4, nn = i & 15;
        size_t o = ((size_t)b * LL + (p0 + inner * j)) * NN + nn;
        sBm[i] = Bm[o];
        sCm[i] = Cm[o];
    }
    const uint32_t* dub = du + (size_t)b * LL * CC + c;
    uint32_t w[CLEN];
    #pragma unroll
    for (int j = 0; j < CLEN; ++j)
        w[j] = dub[(size_t)(p0 + inner * j) * CC];
    float A2[NN];
    {
        const float4* al = (const float4*)(A_log + c * NN);
        #pragma unroll
        for (int q = 0; q < 4; ++q) {
            float4 v = al[q];
            A2[q*4+0] = -expf(v.x) * LOG2E;
            A2[q*4+1] = -expf(v.y) * LOG2E;
            A2[q*4+2] = -expf(v.z) * LOG2E;
            A2[q*4+3] = -expf(v.w) * LOG2E;
        }
    }

    if (sec == 0) {
        int ch2 = 126 - (ch & ~1) + (ch & 1);
        float h0[NN], h2[NN];
        {
            const float4* hp0 = (const float4*)(Hin + ((size_t)(0 * 2 + b) * 128 + ch)  * 4096 + (size_t)c * 16);
            const float4* hp2 = (const float4*)(Hin + ((size_t)(2 * 2 + b) * 128 + ch2) * 4096 + (size_t)c * 16);
            #pragma unroll
            for (int q = 0; q < 4; ++q) {
                float4 v0 = hp0[q], v2 = hp2[q];
                h0[q*4+0]=v0.x; h0[q*4+1]=v0.y; h0[q*4+2]=v0.z; h0[q*4+3]=v0.w;
                h2[q*4+0]=v2.x; h2[q*4+1]=v2.y; h2[q*4+2]=v2.z; h2[q*4+3]=v2.w;
            }
        }
        __syncthreads();
        #pragma unroll
        for (int j = 0; j < CLEN; ++j) {
            float dx = __uint_as_float(w[j] << 16);
            float uy = __uint_as_float(w[j] & 0xffff0000u);
            float dA[NN];
            #pragma unroll
            for (int nn = 0; nn < NN; ++nn) dA[nn] = __builtin_amdgcn_exp2f(A2[nn] * dx);
            float y0v = 0.f, y2v = 0.f;
            #pragma unroll
            for (int nn = 0; nn < NN; ++nn) {
                float Bu = uy * sBm[j * 16 + nn];
                float cm = sCm[j * 16 + nn];
                h0[nn] = fmaf(dA[nn], h0[nn], Bu);
                h2[nn] = fmaf(dA[nn], h2[nn], Bu);
                y0v = fmaf(h0[nn], cm, y0v);
                y2v = fmaf(h2[nn], cm, y2v);
            }
            yA[((size_t)b * LL + p0 + j) * CC + c] = 0.25f * (y0v + y2v);
        }
    } else {
        int d = (sec == 1) ? 1 : 3;
        float h[NN];
        {
            const float4* hp = (const float4*)(Hin + ((size_t)(d * 2 + b) * 128 + ch) * 4096 + (size_t)c * 16);
            #pragma unroll
            for (int q = 0; q < 4; ++q) {
                float4 v = hp[q];
                h[q*4+0]=v.x; h[q*4+1]=v.y; h[q*4+2]=v.z; h[q*4+3]=v.w;
            }
        }
        __syncthreads();
        float* yD = (sec == 1) ? yB : yC;
        #pragma unroll
        for (int j = 0; j < CLEN; ++j) {
            float dx = __uint_as_float(w[j] << 16);
            float uy = __uint_as_float(w[j] & 0xffff0000u);
            float dA[NN];
            #pragma unroll
            for (int nn = 0; nn < NN; ++nn) dA[nn] = __builtin_amdgcn_exp2f(A2[nn] * dx);
            float yv = 0.f;
            #pragma unroll
            for (int nn = 0; nn < NN; ++nn) {
                float Bu = uy * sBm[j * 16 + nn];
                h[nn] = fmaf(dA[nn], h[nn], Bu);
                yv = fmaf(h[nn], sCm[j * 16 + nn], yv);
            }
            yD[((size_t)b * LL + p0 + inner * j) * CC + c] = 0.25f * yv;
        }
    }
}

// ---------------- K6: sum 3 y-buffers + x*D, transpose to (B,C,L) -----------
__global__ __launch_bounds__(256) void k6_reduce(
    const float* __restrict__ feat, const float* __restrict__ D,
    const float* __restrict__ yA, const float* __restrict__ yB,
    const float* __restrict__ yC, float* __restrict__ out)
{
    int pt = blockIdx.x & 63;
    int ct = (blockIdx.x >> 6) & 3;
    int b  = blockIdx.x >> 8;
    int p0 = pt * 64, c0 = ct * 64;
    __shared__ float tile[64 * 65];
    {
        int cl = threadIdx.x & 63;
        int pg = threadIdx.x >> 6;
        #pragma unroll
        for (int pp = 0; pp < 16; ++pp) {
            int pl = pp * 4 + pg;
            size_t ix = ((size_t)b * LL + p0 + pl) * CC + c0 + cl;
            tile[cl * 65 + pl] = yA[ix] + yB[ix] + yC[ix];
        }
    }
    __syncthreads();
    {
        int pl = threadIdx.x & 63;
        int cg = threadIdx.x >> 6;
        #pragma unroll
        for (int cc = 0; cc < 16; ++cc) {
            int cloc = cc * 4 + cg;
            int c = c0 + cloc;
            size_t o = ((size_t)b * CC + c) * LL + p0 + pl;
            out[o] = tile[cloc * 65 + pl] + feat[o] * D[c];
        }
    }
}

extern "C" void kernel_launch(void* const* d_in, const int* in_sizes, int n_in,
                              void* d_out, int out_size, void* d_ws, size_t ws_size,
                              hipStream_t stream)
{
    const float* feat  = (const float*)d_in[0];
    const float* A_log = (const float*)d_in[1];
    const float* D     = (const float*)d_in[2];
    const float* Wd    = (const float*)d_in[3];
    const float* bd    = (const float*)d_in[4];
    const float* WB    = (const float*)d_in[5];
    const float* WC    = (const float*)d_in[6];
    float* out = (float*)d_out;

    float* ws  = (float*)d_ws;
    uint32_t* du = (uint32_t*)ws;                         //  2,097,152 u32 (bf16x2)
    float* Bm  = ws  + (size_t)2097152;                   //    131,072
    float* Cm  = Bm  + (size_t)131072;                    //    131,072
    float* P   = Cm  + (size_t)131072;                    //  3,145,728 (3 cls)
    float* S   = P   + (size_t)3145728;                   //  3,145,728
    float* Hin = S   + (size_t)3145728;                   //  4,194,304 (4 dirs)
    float* yA  = Hin + (size_t)4194304;                   //  2,097,152
    float* yB  = yA  + (size_t)2097152;                   //  2,097,152
    float* yC  = yB  + (size_t)2097152;                   //  2,097,152

    k1_mfma<<<1024, 256, 0, stream>>>(feat, Wd, bd, WB, WC, du, Bm, Cm);
    p1_aggr<<<768, 256, 0, stream>>>(du, Bm, A_log, P, S);
    p2_scan<<<256, 128, 0, stream>>>(P, S, Hin);
    p3_replay<<<768, 256, 0, stream>>>(du, Bm, Cm, A_log, Hin, yA, yB, yC);
    k6_reduce<<<512, 256, 0, stream>>>(feat, D, yA, yB, yC, out);
}